// Round 6
// baseline (222.541 us; speedup 1.0000x reference)
//
#include <hip/hip_runtime.h>
#include <math.h>

// Problem constants (match reference: B,C,W,H,D = 2,256,32,32,32)
#define Bc   2
#define Cc   256
#define Nn   32768            // W*H*D
#define CHc  128              // C/2
#define LN_EPS 1e-5f

// R12 tiling: R8 phase structure, TN doubled to 128 (2 x float4 per row)
#define TN    128             // spatial positions per tile (block)
#define TPB   512             // threads per block (8 waves)
#define NQ    16              // n-quads... n-octs per tile (TN/8)
#define CPG   8               // channels per group (Cc/32)
#define GRIDX (Nn / TN)       // 256 -> x Bc = 512 blocks
#define NSLOT 32              // atomic-contention slots

// ---------------------------------------------------------------------------
// R12 gc_fused: R8's exact 6-barrier cred structure (best: 45.5us), with the
// per-thread row segment doubled 16B -> 32B (two adjacent float4).
//
// Evidence: R9 (1 barrier) and R11 (2 barriers, half the atomics) both
// landed 47-53us -> barriers/atomics/LDS are NOT the bottleneck. Invariant
// = bytes at 2.8 TB/s effective (1.44 HBM + ~1.4 L3). m13's 6.3 TB/s was
// full-wave LINEAR streaming; our requests are 256B runs (16 lanes x 16B).
// R12 tests the contiguity axis: 512B runs + 2x bytes in flight per wave.
// __launch_bounds__(512,2) = 256-VGPR cap (R10's spill was the ",4" cap;
// R11 proved ",2" spill-free). Health check: WRITE_SIZE stays ~3MB.
// UNSHIFTED softmax (shift-invariant; |mask| <~ 2, fp32-exact).
// ---------------------------------------------------------------------------
__global__ __launch_bounds__(TPB, 2) void gc_fused(
    const float* __restrict__ S, const float* __restrict__ T,
    const float* __restrict__ wms, const float* __restrict__ bms,
    const float* __restrict__ wmt, const float* __restrict__ bmt,
    float* __restrict__ ctxnum,   // [NSLOT][2][Bc][Cc] raw weighted sums
    float* __restrict__ rowsum,   // [NSLOT][Bc][Cc]
    float* __restrict__ den,      // [NSLOT][4] softmax denominators
    float* __restrict__ sumsq) {  // [NSLOT]
  const int b    = blockIdx.y;
  const int tid  = threadIdx.x;
  const int nq   = tid & (NQ - 1);
  const int cg   = tid >> 4;
  const int wv   = tid >> 6;
  const int lane = tid & 63;
  const int c0   = cg * CPG;
  const int n0   = blockIdx.x * TN + nq * 8;   // 8 consecutive n per thread
  const int slot = blockIdx.x & (NSLOT - 1);

  __shared__ float4 mredwA[2][8][NQ];  // 4 KB   wave mask partials (n 0..3)
  __shared__ float4 mredwB[2][8][NQ];  // 4 KB   wave mask partials (n 4..7)
  __shared__ float  cred[Cc * 17];     // 17 KB  reused channel-partial buffer
  __shared__ float  sqred[8];
  __shared__ float  denred[2][NQ];

  const float bS = bms[0];
  const float bT = bmt[0];

  const float* Sp = S + ((size_t)b * Cc + c0) * Nn + n0;
  const float* Tp = T + ((size_t)b * Cc + c0) * Nn + n0;

  // ---- issue all 32 independent tile loads up front (32B run per row) ----
  float4 sa[CPG], sb[CPG], ta[CPG], tb[CPG];
#pragma unroll
  for (int i = 0; i < CPG; ++i) {
    sa[i] = *(const float4*)(Sp + (size_t)i * Nn);
    sb[i] = *(const float4*)(Sp + (size_t)i * Nn + 4);
  }
#pragma unroll
  for (int i = 0; i < CPG; ++i) {
    ta[i] = *(const float4*)(Tp + (size_t)i * Nn);
    tb[i] = *(const float4*)(Tp + (size_t)i * Nn + 4);
  }

  float wS[CPG], wT[CPG];
#pragma unroll
  for (int i = 0; i < CPG; ++i) { wS[i] = wms[c0 + i]; wT[i] = wmt[c0 + i]; }

  // ---- mask partials (two float4 accumulators per tensor) ----
  float4 msa = make_float4(0.f, 0.f, 0.f, 0.f);
  float4 msb = make_float4(0.f, 0.f, 0.f, 0.f);
  float4 mta = make_float4(0.f, 0.f, 0.f, 0.f);
  float4 mtb = make_float4(0.f, 0.f, 0.f, 0.f);
#pragma unroll
  for (int i = 0; i < CPG; ++i) {
    msa.x += wS[i] * sa[i].x; msa.y += wS[i] * sa[i].y;
    msa.z += wS[i] * sa[i].z; msa.w += wS[i] * sa[i].w;
    msb.x += wS[i] * sb[i].x; msb.y += wS[i] * sb[i].y;
    msb.z += wS[i] * sb[i].z; msb.w += wS[i] * sb[i].w;
    mta.x += wT[i] * ta[i].x; mta.y += wT[i] * ta[i].y;
    mta.z += wT[i] * ta[i].z; mta.w += wT[i] * ta[i].w;
    mtb.x += wT[i] * tb[i].x; mtb.y += wT[i] * tb[i].y;
    mtb.z += wT[i] * tb[i].z; mtb.w += wT[i] * tb[i].w;
  }

  // butterfly across the wave's 4 cg-subgroups (lane bits 4,5) — no barrier
#pragma unroll
  for (int m = 16; m <= 32; m <<= 1) {
    msa.x += __shfl_xor(msa.x, m); msa.y += __shfl_xor(msa.y, m);
    msa.z += __shfl_xor(msa.z, m); msa.w += __shfl_xor(msa.w, m);
    msb.x += __shfl_xor(msb.x, m); msb.y += __shfl_xor(msb.y, m);
    msb.z += __shfl_xor(msb.z, m); msb.w += __shfl_xor(msb.w, m);
    mta.x += __shfl_xor(mta.x, m); mta.y += __shfl_xor(mta.y, m);
    mta.z += __shfl_xor(mta.z, m); mta.w += __shfl_xor(mta.w, m);
    mtb.x += __shfl_xor(mtb.x, m); mtb.y += __shfl_xor(mtb.y, m);
    mtb.z += __shfl_xor(mtb.z, m); mtb.w += __shfl_xor(mtb.w, m);
  }
  if (lane < NQ) {
    mredwA[0][wv][nq] = msa; mredwA[1][wv][nq] = mta;
    mredwB[0][wv][nq] = msb; mredwB[1][wv][nq] = mtb;
  }

  __syncthreads();   // barrier 1: mask partials visible

  float4 Msa = make_float4(0.f, 0.f, 0.f, 0.f);
  float4 Msb = make_float4(0.f, 0.f, 0.f, 0.f);
  float4 Mta = make_float4(0.f, 0.f, 0.f, 0.f);
  float4 Mtb = make_float4(0.f, 0.f, 0.f, 0.f);
#pragma unroll
  for (int w = 0; w < 8; ++w) {
    const float4 a0 = mredwA[0][w][nq];
    Msa.x += a0.x; Msa.y += a0.y; Msa.z += a0.z; Msa.w += a0.w;
    const float4 b0 = mredwB[0][w][nq];
    Msb.x += b0.x; Msb.y += b0.y; Msb.z += b0.z; Msb.w += b0.w;
    const float4 c1 = mredwA[1][w][nq];
    Mta.x += c1.x; Mta.y += c1.y; Mta.z += c1.z; Mta.w += c1.w;
    const float4 d1 = mredwB[1][w][nq];
    Mtb.x += d1.x; Mtb.y += d1.y; Mtb.z += d1.z; Mtb.w += d1.w;
  }
  float4 esa, esb, eta, etb;
  esa.x = __expf(Msa.x + bS); esa.y = __expf(Msa.y + bS);
  esa.z = __expf(Msa.z + bS); esa.w = __expf(Msa.w + bS);
  esb.x = __expf(Msb.x + bS); esb.y = __expf(Msb.y + bS);
  esb.z = __expf(Msb.z + bS); esb.w = __expf(Msb.w + bS);
  eta.x = __expf(Mta.x + bT); eta.y = __expf(Mta.y + bT);
  eta.z = __expf(Mta.z + bT); eta.w = __expf(Mta.w + bT);
  etb.x = __expf(Mtb.x + bT); etb.y = __expf(Mtb.y + bT);
  etb.z = __expf(Mtb.z + bT); etb.w = __expf(Mtb.w + bT);

  if (tid < NQ) {  // cg==0 threads: one denominator contribution per nq
    denred[0][tid] = esa.x + esa.y + esa.z + esa.w +
                     esb.x + esb.y + esb.z + esb.w;
    denred[1][tid] = eta.x + eta.y + eta.z + eta.w +
                     etb.x + etb.y + etb.z + etb.w;
  }

  // ---- round 1: ctx_s channel partials ----
#pragma unroll
  for (int i = 0; i < CPG; ++i)
    cred[(c0 + i) * 17 + nq] =
        sa[i].x * esa.x + sa[i].y * esa.y + sa[i].z * esa.z + sa[i].w * esa.w +
        sb[i].x * esb.x + sb[i].y * esb.y + sb[i].z * esb.z + sb[i].w * esb.w;
  __syncthreads();   // barrier 2
  if (tid < Cc) {
    float a = 0.f;
#pragma unroll
    for (int k = 0; k < NQ; ++k) a += cred[tid * 17 + k];
    atomicAdd(&ctxnum[(((size_t)slot * 2 + 0) * Bc + b) * Cc + tid], a);
  } else if (tid == Cc + 1) {
    float a = 0.f, c = 0.f;
#pragma unroll
    for (int k = 0; k < NQ; ++k) { a += denred[0][k]; c += denred[1][k]; }
    atomicAdd(&den[slot * 4 + 0 * Bc + b], a);
    atomicAdd(&den[slot * 4 + 1 * Bc + b], c);
  }
  __syncthreads();   // barrier 3 (cred write-after-read guard)

  // ---- round 2: ctx_t channel partials ----
#pragma unroll
  for (int i = 0; i < CPG; ++i)
    cred[(c0 + i) * 17 + nq] =
        ta[i].x * eta.x + ta[i].y * eta.y + ta[i].z * eta.z + ta[i].w * eta.w +
        tb[i].x * etb.x + tb[i].y * etb.y + tb[i].z * etb.z + tb[i].w * etb.w;
  __syncthreads();   // barrier 4
  if (tid < Cc) {
    float c = 0.f;
#pragma unroll
    for (int k = 0; k < NQ; ++k) c += cred[tid * 17 + k];
    atomicAdd(&ctxnum[(((size_t)slot * 2 + 1) * Bc + b) * Cc + tid], c);
  }
  __syncthreads();   // barrier 5

  // ---- round 3: rowsum partials + sumsq (recomputed from live regs) ----
  float sq = 0.f;
#pragma unroll
  for (int i = 0; i < CPG; ++i) {
    const float dxa = sa[i].x - ta[i].x, dya = sa[i].y - ta[i].y;
    const float dza = sa[i].z - ta[i].z, dwa = sa[i].w - ta[i].w;
    const float dxb = sb[i].x - tb[i].x, dyb = sb[i].y - tb[i].y;
    const float dzb = sb[i].z - tb[i].z, dwb = sb[i].w - tb[i].w;
    cred[(c0 + i) * 17 + nq] =
        dxa + dya + dza + dwa + dxb + dyb + dzb + dwb;
    sq += dxa * dxa + dya * dya + dza * dza + dwa * dwa +
          dxb * dxb + dyb * dyb + dzb * dzb + dwb * dwb;
  }
#pragma unroll
  for (int m = 1; m < 64; m <<= 1) sq += __shfl_xor(sq, m);
  if (lane == 0) sqred[wv] = sq;
  __syncthreads();   // barrier 6
  if (tid < Cc) {
    float r = 0.f;
#pragma unroll
    for (int k = 0; k < NQ; ++k) r += cred[tid * 17 + k];
    atomicAdd(&rowsum[((size_t)slot * Bc + b) * Cc + tid], r);
  } else if (tid == Cc) {
    float v = 0.f;
#pragma unroll
    for (int w = 0; w < 8; ++w) v += sqred[w];
    atomicAdd(&sumsq[slot], v);
  }
}

// ---------------------------------------------------------------------------
// R12 gc_k4: k4a+k4b merged into ONE block (no cross-block fences — R7's
// mistake avoided). 1024 threads = 4 groups of 256; group g = (tt,b) runs
// its MLP on its own LDS slice; all groups share the same barrier cadence.
// Final scalar computed from LDS addv at the end. Saves one dispatch.
// ---------------------------------------------------------------------------
__global__ __launch_bounds__(1024) void gc_k4(
    const float* __restrict__ ctxr, const float* __restrict__ den,
    const float* __restrict__ w1s, const float* __restrict__ b1s,
    const float* __restrict__ gs,  const float* __restrict__ bes,
    const float* __restrict__ w2s, const float* __restrict__ b2s,
    const float* __restrict__ w1t, const float* __restrict__ b1t,
    const float* __restrict__ gt,  const float* __restrict__ bet,
    const float* __restrict__ w2t, const float* __restrict__ b2t,
    const float* __restrict__ rowsum, const float* __restrict__ sumsq,
    float* __restrict__ out) {
  const int tid  = threadIdx.x;
  const int grp  = tid >> 8;          // 0..3 = tt*2 + b
  const int tt   = grp >> 1;
  const int b    = grp & 1;
  const int gtid = tid & 255;

  const float* w1 = tt ? w1t : w1s;
  const float* b1 = tt ? b1t : b1s;
  const float* g  = tt ? gt  : gs;
  const float* be = tt ? bet : bes;
  const float* w2 = tt ? w2t : w2s;
  const float* b2 = tt ? b2t : b2s;

  __shared__ float  cxs[4][Cc];       // 4 KB
  __shared__ float  part[4][256];     // 4 KB
  __shared__ float  hbuf[4][CHc];     // 2 KB
  __shared__ float  hr[4][CHc];       // 2 KB
  __shared__ float2 red2[4][64];      // 2 KB
  __shared__ float  mu_s[4], rstd_s[4];
  __shared__ float  rsf[Bc * Cc];     // 2 KB  folded rowsum
  __shared__ float  addv_l[4][Cc];    // 4 KB
  __shared__ float  red[512];         // 2 KB

  // fold ctx numerator/denominator slots
  {
    float num = 0.f, dn = 0.f;
#pragma unroll
    for (int k = 0; k < NSLOT; ++k) {
      num += ctxr[(((size_t)k * 2 + tt) * Bc + b) * Cc + gtid];
      dn  += den[k * 4 + tt * Bc + b];
    }
    cxs[grp][gtid] = num / dn;
  }
  // fold rowsum slots (512 (b,c) pairs; threads 0..511)
  if (tid < Bc * Cc) {
    const int c = tid & (Cc - 1);
    const int bb = tid >> 8;
    float rs = 0.f;
#pragma unroll
    for (int k = 0; k < NSLOT; ++k)
      rs += rowsum[((size_t)k * Bc + bb) * Cc + c];
    rsf[tid] = rs;
  }
  __syncthreads();

  // stage 1: h[j] = sum_c ctx[c]*w1[j][c] + b1[j]  (128 j x 2 half-dots)
  {
    const int j = gtid >> 1, s = gtid & 1;
    const float* wr = w1 + j * Cc + s * 128;
    const float4* cx4 = (const float4*)(&cxs[grp][s * 128]);
    float acc = 0.f;
#pragma unroll
    for (int kk = 0; kk < 32; ++kk) {
      const float4 w = *(const float4*)(wr + kk * 4);
      const float4 x = cx4[kk];
      acc += w.x * x.x + w.y * x.y + w.z * x.z + w.w * x.w;
    }
    part[grp][gtid] = acc;
  }
  __syncthreads();
  if (gtid < CHc)
    hbuf[grp][gtid] = b1[gtid] + part[grp][2 * gtid] + part[grp][2 * gtid + 1];
  __syncthreads();

  // LN stats over 128 per group
  if (gtid < 64) {
    const float v0 = hbuf[grp][gtid], v1 = hbuf[grp][gtid + 64];
    red2[grp][gtid] = make_float2(v0 + v1, v0 * v0 + v1 * v1);
  }
  __syncthreads();
  for (int s = 32; s > 0; s >>= 1) {
    if (gtid < s) {
      red2[grp][gtid].x += red2[grp][gtid + s].x;
      red2[grp][gtid].y += red2[grp][gtid + s].y;
    }
    __syncthreads();
  }
  if (gtid == 0) {
    const float mu = red2[grp][0].x / (float)CHc;
    const float var = red2[grp][0].y / (float)CHc - mu * mu;
    mu_s[grp] = mu;
    rstd_s[grp] = rsqrtf(var + LN_EPS);
  }
  __syncthreads();
  if (gtid < CHc) {
    const float v =
        (hbuf[grp][gtid] - mu_s[grp]) * rstd_s[grp] * g[gtid] + be[gtid];
    hr[grp][gtid] = v > 0.f ? v : 0.f;
  }
  __syncthreads();

  // stage 3: addv[c] = sum_j hr[j]*w2[c][j] + b2[c]  (256 c, full 128-dot)
  {
    const float* wr = w2 + gtid * CHc;
    const float4* h4 = (const float4*)(&hr[grp][0]);
    float acc = b2[gtid];
#pragma unroll
    for (int kk = 0; kk < 32; ++kk) {
      const float4 w = *(const float4*)(wr + kk * 4);
      const float4 x = h4[kk];
      acc += w.x * x.x + w.y * x.y + w.z * x.z + w.w * x.w;
    }
    addv_l[grp][gtid] = acc;
  }
  __syncthreads();

  // final scalar: 512 jobs (bb,c)
  if (tid < Bc * Cc) {
    const int c = tid & (Cc - 1);
    const int bb = tid >> 8;
    const float delta = addv_l[0 + bb][c] - addv_l[2 + bb][c];
    red[tid] = 2.f * delta * rsf[tid] + (float)Nn * delta * delta;
  }
  __syncthreads();
  for (int s = 256; s > 0; s >>= 1) {
    if (tid < s) red[tid] += red[tid + s];
    __syncthreads();
  }
  if (tid == 0) {
    float sq = 0.f;
#pragma unroll
    for (int k = 0; k < NSLOT; ++k) sq += sumsq[k];
    out[0] = (red[0] + sq) / (float)Bc;
  }
}

// ---------------------------------------------------------------------------
extern "C" void kernel_launch(void* const* d_in, const int* in_sizes, int n_in,
                              void* d_out, int out_size, void* d_ws,
                              size_t ws_size, hipStream_t stream) {
  const float* S   = (const float*)d_in[0];
  const float* T   = (const float*)d_in[1];
  const float* wms = (const float*)d_in[2];
  const float* bms = (const float*)d_in[3];
  const float* wmt = (const float*)d_in[4];
  const float* bmt = (const float*)d_in[5];
  const float* w1s = (const float*)d_in[6];
  const float* b1s = (const float*)d_in[7];
  const float* gs  = (const float*)d_in[8];
  const float* bes = (const float*)d_in[9];
  const float* w2s = (const float*)d_in[10];
  const float* b2s = (const float*)d_in[11];
  const float* w1t = (const float*)d_in[12];
  const float* b1t = (const float*)d_in[13];
  const float* gt  = (const float*)d_in[14];
  const float* bet = (const float*)d_in[15];
  const float* w2t = (const float*)d_in[16];
  const float* b2t = (const float*)d_in[17];
  float* out = (float*)d_out;

  // ws layout (floats) — slotted accumulators first; one memset zeroes all.
  float* ws     = (float*)d_ws;
  float* ctxnum = ws;                               // NSLOT*2*B*C = 32768
  float* rowsum = ctxnum + NSLOT * 2 * Bc * Cc;     // NSLOT*B*C   = 16384
  float* den    = rowsum + NSLOT * Bc * Cc;         // NSLOT*4     = 128
  float* sumsq  = den + NSLOT * 4;                  // NSLOT       = 32

  hipMemsetAsync(d_ws, 0,
                 (NSLOT * (2 * Bc * Cc + Bc * Cc + 4 + 1)) * sizeof(float),
                 stream);

  gc_fused<<<dim3(GRIDX, Bc), TPB, 0, stream>>>(S, T, wms, bms, wmt, bmt,
                                                ctxnum, rowsum, den, sumsq);
  gc_k4<<<1, 1024, 0, stream>>>(ctxnum, den, w1s, b1s, gs, bes, w2s, b2s,
                                w1t, b1t, gt, bet, w2t, b2t,
                                rowsum, sumsq, out);
}

// Round 8
// 203.563 us; speedup vs baseline: 1.0932x; 1.0932x over previous
//
#include <hip/hip_runtime.h>
#include <math.h>

// Problem constants (match reference: B,C,W,H,D = 2,256,32,32,32)
#define Bc   2
#define Cc   256
#define Nn   32768            // W*H*D
#define CHc  128              // C/2
#define LN_EPS 1e-5f

// R13 tiling: 1 block/CU, 4 tiles/block, register double-buffer
#define TN    64              // spatial positions per tile
#define ITERS 4               // tiles per block
#define TPB   512             // threads per block (8 waves)
#define NQ    16              // n-quads per tile (TN/4)
#define CPG   8               // channels per thread (32 groups x 8 = 256)
#define GRIDX (Nn / (TN * ITERS))   // 128 -> x Bc = 256 blocks = 1/CU
#define NSLOT 32              // atomic-contention slots

// ---------------------------------------------------------------------------
// R13 gc_fused (resubmit: R7 bench was an infra failure, no data).
// Continuous-memory schedule.
//
// Model (from R12's gc_k4 datum: 1 CU streams ~1MB at ~22 GB/s): per-CU read
// throughput is miss-queue limited (~60 lines x 128B / ~750cy ~ 25 GB/s/CU).
// R8/R11/R12 all ran at ~11 GB/s/CU = ~45% memory duty cycle: one 1024-line
// burst per block, then thousands of barrier-phase cycles with no loads.
// R13: 1 block/CU (grid 256), ITERS=4, register DOUBLE-BUFFER. Next tile's
// 16 float4 loads issue at the TOP of each body -> in flight across
// phase1+B1+phase2+phase3 (~2K cy >> 750cy). launch_bounds(512,2) = 256-VGPR
// cap: two tiles (128 regs) + ~60 others fit with NO spill (R10's spill was
// the ",4"/128-VGPR cap; health check = WRITE_SIZE stays ~1.6MB).
// Per-tile body = R11's verified 2-barrier / 3-cred-buffer structure.
// Accumulators in registers; ONE atomic tail per block. NSLOT=32.
// UNSHIFTED softmax (shift-invariant; |mask| <~ 2, fp32-exact).
// ---------------------------------------------------------------------------
__global__ __launch_bounds__(TPB, 2) void gc_fused(
    const float* __restrict__ S, const float* __restrict__ T,
    const float* __restrict__ wms, const float* __restrict__ bms,
    const float* __restrict__ wmt, const float* __restrict__ bmt,
    float* __restrict__ ctxnum,   // [NSLOT][2][Bc][Cc] raw weighted sums
    float* __restrict__ rowsum,   // [NSLOT][Bc][Cc]
    float* __restrict__ den,      // [NSLOT][4] softmax denominators
    float* __restrict__ sumsq) {  // [NSLOT]
  const int b    = blockIdx.y;
  const int tid  = threadIdx.x;
  const int nq   = tid & (NQ - 1);
  const int cg   = tid >> 4;           // 0..31
  const int wv   = tid >> 6;
  const int lane = tid & 63;
  const int c0   = cg * CPG;
  const int slot = blockIdx.x & (NSLOT - 1);
  const int nbase = blockIdx.x * (ITERS * TN) + nq * 4;

  __shared__ float4 mredw[2][8][NQ];   // 4 KB   wave-level mask partials
  __shared__ float  creds[Cc * 17];    // 17 KB  ctx_s partials
  __shared__ float  credt[Cc * 17];    // 17 KB  ctx_t partials
  __shared__ float  credd[Cc * 17];    // 17 KB  rowsum partials
  __shared__ float  sqred[8];

  const float bS = bms[0];
  const float bT = bmt[0];

  const float* Sp = S + ((size_t)b * Cc + c0) * Nn + nbase;
  const float* Tp = T + ((size_t)b * Cc + c0) * Nn + nbase;

  float wS[CPG], wT[CPG];
#pragma unroll
  for (int i = 0; i < CPG; ++i) { wS[i] = wms[c0 + i]; wT[i] = wmt[c0 + i]; }

  // running accumulators across the tiles
  float accS = 0.f, accT = 0.f, accR = 0.f;
  float dens = 0.f, dent = 0.f, sq = 0.f;

  float4 sA[CPG], tA[CPG], sB[CPG], tB[CPG];

  // prologue: tile 0 into A
#pragma unroll
  for (int i = 0; i < CPG; ++i) sA[i] = *(const float4*)(Sp + (size_t)i * Nn);
#pragma unroll
  for (int i = 0; i < CPG; ++i) tA[i] = *(const float4*)(Tp + (size_t)i * Nn);

  // Per-tile body: prefetch NEXT tile into NS/NT first (flies across
  // phase1+B1+phase2+phase3), then process CS/CT with R11's 2-barrier
  // structure. Static register naming (rule #20).
#define GC_BODY(CS, CT, NS, NT, IT, HASNEXT)                                  \
  do {                                                                        \
    if (HASNEXT) {                                                            \
      _Pragma("unroll") for (int i = 0; i < CPG; ++i)                         \
          NS[i] = *(const float4*)(Sp + (size_t)i * Nn + ((IT) + 1) * TN);    \
      _Pragma("unroll") for (int i = 0; i < CPG; ++i)                         \
          NT[i] = *(const float4*)(Tp + (size_t)i * Nn + ((IT) + 1) * TN);    \
    }                                                                         \
    /* phase 1: mask partials */                                              \
    float4 ms = make_float4(0.f, 0.f, 0.f, 0.f);                              \
    float4 mt = make_float4(0.f, 0.f, 0.f, 0.f);                              \
    _Pragma("unroll") for (int i = 0; i < CPG; ++i) {                         \
      ms.x += wS[i] * CS[i].x; ms.y += wS[i] * CS[i].y;                       \
      ms.z += wS[i] * CS[i].z; ms.w += wS[i] * CS[i].w;                       \
      mt.x += wT[i] * CT[i].x; mt.y += wT[i] * CT[i].y;                       \
      mt.z += wT[i] * CT[i].z; mt.w += wT[i] * CT[i].w;                       \
    }                                                                         \
    _Pragma("unroll") for (int m = 16; m <= 32; m <<= 1) {                    \
      ms.x += __shfl_xor(ms.x, m); ms.y += __shfl_xor(ms.y, m);               \
      ms.z += __shfl_xor(ms.z, m); ms.w += __shfl_xor(ms.w, m);               \
      mt.x += __shfl_xor(mt.x, m); mt.y += __shfl_xor(mt.y, m);               \
      mt.z += __shfl_xor(mt.z, m); mt.w += __shfl_xor(mt.w, m);               \
    }                                                                         \
    if (lane < NQ) { mredw[0][wv][nq] = ms; mredw[1][wv][nq] = mt; }          \
    __syncthreads(); /* B1 */                                                 \
    /* phase 2: assemble mask, exp */                                         \
    float4 Ms = make_float4(0.f, 0.f, 0.f, 0.f);                              \
    float4 Mt = make_float4(0.f, 0.f, 0.f, 0.f);                              \
    _Pragma("unroll") for (int w = 0; w < 8; ++w) {                           \
      const float4 a = mredw[0][w][nq];                                       \
      Ms.x += a.x; Ms.y += a.y; Ms.z += a.z; Ms.w += a.w;                     \
      const float4 c = mredw[1][w][nq];                                       \
      Mt.x += c.x; Mt.y += c.y; Mt.z += c.z; Mt.w += c.w;                     \
    }                                                                         \
    float4 es, et;                                                            \
    es.x = __expf(Ms.x + bS); es.y = __expf(Ms.y + bS);                       \
    es.z = __expf(Ms.z + bS); es.w = __expf(Ms.w + bS);                       \
    et.x = __expf(Mt.x + bT); et.y = __expf(Mt.y + bT);                       \
    et.z = __expf(Mt.z + bT); et.w = __expf(Mt.w + bT);                       \
    dens += es.x + es.y + es.z + es.w;                                        \
    dent += et.x + et.y + et.z + et.w;                                        \
    /* phase 3: write all three partial sets */                               \
    _Pragma("unroll") for (int i = 0; i < CPG; ++i) {                         \
      creds[(c0 + i) * 17 + nq] = CS[i].x * es.x + CS[i].y * es.y +           \
                                  CS[i].z * es.z + CS[i].w * es.w;            \
      credt[(c0 + i) * 17 + nq] = CT[i].x * et.x + CT[i].y * et.y +           \
                                  CT[i].z * et.z + CT[i].w * et.w;            \
      const float dx = CS[i].x - CT[i].x, dy = CS[i].y - CT[i].y;             \
      const float dz = CS[i].z - CT[i].z, dw = CS[i].w - CT[i].w;             \
      credd[(c0 + i) * 17 + nq] = dx + dy + dz + dw;                          \
      sq += dx * dx + dy * dy + dz * dz + dw * dw;                            \
    }                                                                         \
    __syncthreads(); /* B2 */                                                 \
    /* phase 4: LDS accumulate */                                             \
    if (tid < Cc) {                                                           \
      float a = 0.f, r = 0.f;                                                 \
      _Pragma("unroll") for (int k = 0; k < NQ; ++k) {                        \
        a += creds[tid * 17 + k];                                             \
        r += credd[tid * 17 + k];                                             \
      }                                                                       \
      accS += a; accR += r;                                                   \
    } else {                                                                  \
      float t = 0.f;                                                          \
      _Pragma("unroll") for (int k = 0; k < NQ; ++k)                          \
          t += credt[(tid - Cc) * 17 + k];                                    \
      accT += t;                                                              \
    }                                                                         \
  } while (0)

  GC_BODY(sA, tA, sB, tB, 0, 1);
  GC_BODY(sB, tB, sA, tA, 1, 1);
  GC_BODY(sA, tA, sB, tB, 2, 1);
  GC_BODY(sB, tB, sA, tA, 3, 0);
#undef GC_BODY

  // ---- epilogue: one atomic phase per block ----
#pragma unroll
  for (int m = 1; m < 64; m <<= 1) sq += __shfl_xor(sq, m);
  if (lane == 0) sqred[wv] = sq;
  // dens/dent identical across the 4 cg-subgroups; sum the 16 nq lanes
#pragma unroll
  for (int m = 1; m <= 8; m <<= 1) {
    dens += __shfl_xor(dens, m);
    dent += __shfl_xor(dent, m);
  }
  __syncthreads();   // sqred visible

  if (tid < Cc) {
    atomicAdd(&ctxnum[(((size_t)slot * 2 + 0) * Bc + b) * Cc + tid], accS);
    atomicAdd(&rowsum[((size_t)slot * Bc + b) * Cc + tid], accR);
  } else {
    atomicAdd(&ctxnum[(((size_t)slot * 2 + 1) * Bc + b) * Cc + (tid - Cc)],
              accT);
  }
  if (tid == 0) {
    atomicAdd(&den[slot * 4 + 0 * Bc + b], dens);
    atomicAdd(&den[slot * 4 + 1 * Bc + b], dent);
    float v = 0.f;
#pragma unroll
    for (int w = 0; w < 8; ++w) v += sqred[w];
    atomicAdd(&sumsq[slot], v);
  }
}

// ---------------------------------------------------------------------------
// K4a: channel_add MLP per (tt,b). grid 4, block 1024 (REVERTED from R12's
// 1-block merge, which cost +25us: single-CU cold streaming ~22 GB/s).
// New: stage-3 w2 row preloaded at kernel start -> its fetch latency hides
// under stages 1-2. ctx = fold NSLOT slots at load time.
// ---------------------------------------------------------------------------
__global__ __launch_bounds__(1024) void gc_k4a_mlp(
    const float* __restrict__ ctxr, const float* __restrict__ den,
    const float* __restrict__ w1s, const float* __restrict__ b1s,
    const float* __restrict__ gs,  const float* __restrict__ bes,
    const float* __restrict__ w2s, const float* __restrict__ b2s,
    const float* __restrict__ w1t, const float* __restrict__ b1t,
    const float* __restrict__ gt,  const float* __restrict__ bet,
    const float* __restrict__ w2t, const float* __restrict__ b2t,
    float* __restrict__ addv) {
  const int tt  = blockIdx.x >> 1;
  const int b   = blockIdx.x & 1;
  const int tid = threadIdx.x;

  const float* w1 = tt ? w1t : w1s;
  const float* b1 = tt ? b1t : b1s;
  const float* g  = tt ? gt  : gs;
  const float* be = tt ? bet : bes;
  const float* w2 = tt ? w2t : w2s;
  const float* b2 = tt ? b2t : b2s;

  __shared__ float cxs[Cc];
  __shared__ float part[1024];
  __shared__ float hbuf[CHc];
  __shared__ float hr[CHc];
  __shared__ float2 red2[128];
  __shared__ float mu_s, rstd_s;

  // ---- preload stage-3 weights early (consumed after LN) ----
  const int c3 = tid >> 2, q3 = tid & 3;
  const float* wr3 = w2 + c3 * CHc + q3 * 32;
  float4 w2r[8];
#pragma unroll
  for (int kk = 0; kk < 8; ++kk) w2r[kk] = *(const float4*)(wr3 + kk * 4);

  if (tid < Cc) {
    float num = 0.f, dn = 0.f;
#pragma unroll
    for (int kk = 0; kk < NSLOT; ++kk) {
      num += ctxr[(((size_t)kk * 2 + tt) * Bc + b) * Cc + tid];
      dn  += den[kk * 4 + tt * Bc + b];
    }
    cxs[tid] = num / dn;
  }
  __syncthreads();

  // stage 1: h[j] = sum_c ctx[c]*w1[j][c] + b1[j]   (128 j x 8 segments)
  {
    const int j = tid >> 3, s = tid & 7;
    const float* wr = w1 + j * Cc + s * 32;
    const float4* cx4 = (const float4*)(cxs + s * 32);
    float acc = 0.f;
#pragma unroll
    for (int kk = 0; kk < 8; ++kk) {
      const float4 w = *(const float4*)(wr + kk * 4);
      const float4 x = cx4[kk];
      acc += w.x * x.x + w.y * x.y + w.z * x.z + w.w * x.w;
    }
    part[tid] = acc;
  }
  __syncthreads();
  if (tid < CHc) {
    float h = b1[tid];
#pragma unroll
    for (int q = 0; q < 8; ++q) h += part[tid * 8 + q];
    hbuf[tid] = h;
  }
  __syncthreads();

  // LN stats over 128
  if (tid < CHc) {
    const float v = hbuf[tid];
    red2[tid] = make_float2(v, v * v);
  }
  __syncthreads();
  for (int s = 64; s > 0; s >>= 1) {
    if (tid < s) {
      red2[tid].x += red2[tid + s].x;
      red2[tid].y += red2[tid + s].y;
    }
    __syncthreads();
  }
  if (tid == 0) {
    const float mu = red2[0].x / (float)CHc;
    const float var = red2[0].y / (float)CHc - mu * mu;
    mu_s = mu;
    rstd_s = rsqrtf(var + LN_EPS);
  }
  __syncthreads();
  if (tid < CHc) {
    const float v = (hbuf[tid] - mu_s) * rstd_s * g[tid] + be[tid];
    hr[tid] = v > 0.f ? v : 0.f;
  }
  __syncthreads();

  // stage 3: addv[c] = sum_j hr[j]*w2[c][j] + b2[c]   (256 c x 4 segments)
  {
    const float4* h4 = (const float4*)(hr + q3 * 32);
    float acc = 0.f;
#pragma unroll
    for (int kk = 0; kk < 8; ++kk) {
      const float4 w = w2r[kk];
      const float4 x = h4[kk];
      acc += w.x * x.x + w.y * x.y + w.z * x.z + w.w * x.w;
    }
    part[tid] = acc;
  }
  __syncthreads();
  if (tid < Cc) {
    float acc = b2[tid];
#pragma unroll
    for (int q = 0; q < 4; ++q) acc += part[tid * 4 + q];
    addv[((size_t)tt * Bc + b) * Cc + tid] = acc;
  }
}

// ---------------------------------------------------------------------------
// K4b: final scalar. 1 block, 256 thr. Folds the NSLOT rowsum/sumsq slots.
// out = (sumsq + sum_{b,c} [2*delta*rowsum + N*delta^2]) / B
// ---------------------------------------------------------------------------
__global__ __launch_bounds__(256) void gc_k4b_final(
    const float* __restrict__ addv, const float* __restrict__ rowsum,
    const float* __restrict__ sumsq, float* __restrict__ out) {
  const int tid = threadIdx.x;
  __shared__ float red[256];
  float part = 0.f;
  for (int job = tid; job < Bc * Cc; job += 256) {
    const int c = job & (Cc - 1);
    const int b = job >> 8;
    const float delta = addv[((size_t)0 * Bc + b) * Cc + c] -
                        addv[((size_t)1 * Bc + b) * Cc + c];
    float rs = 0.f;
#pragma unroll
    for (int k = 0; k < NSLOT; ++k)
      rs += rowsum[((size_t)k * Bc + b) * Cc + c];
    part += 2.f * delta * rs + (float)Nn * delta * delta;
  }
  red[tid] = part;
  __syncthreads();
  for (int s = 128; s > 0; s >>= 1) {
    if (tid < s) red[tid] += red[tid + s];
    __syncthreads();
  }
  if (tid == 0) {
    float sq = 0.f;
#pragma unroll
    for (int k = 0; k < NSLOT; ++k) sq += sumsq[k];
    out[0] = (red[0] + sq) / (float)Bc;
  }
}

// ---------------------------------------------------------------------------
extern "C" void kernel_launch(void* const* d_in, const int* in_sizes, int n_in,
                              void* d_out, int out_size, void* d_ws,
                              size_t ws_size, hipStream_t stream) {
  const float* S   = (const float*)d_in[0];
  const float* T   = (const float*)d_in[1];
  const float* wms = (const float*)d_in[2];
  const float* bms = (const float*)d_in[3];
  const float* wmt = (const float*)d_in[4];
  const float* bmt = (const float*)d_in[5];
  const float* w1s = (const float*)d_in[6];
  const float* b1s = (const float*)d_in[7];
  const float* gs  = (const float*)d_in[8];
  const float* bes = (const float*)d_in[9];
  const float* w2s = (const float*)d_in[10];
  const float* b2s = (const float*)d_in[11];
  const float* w1t = (const float*)d_in[12];
  const float* b1t = (const float*)d_in[13];
  const float* gt  = (const float*)d_in[14];
  const float* bet = (const float*)d_in[15];
  const float* w2t = (const float*)d_in[16];
  const float* b2t = (const float*)d_in[17];
  float* out = (float*)d_out;

  // ws layout (floats) — slotted accumulators first; one memset zeroes all.
  float* ws     = (float*)d_ws;
  float* ctxnum = ws;                               // NSLOT*2*B*C = 32768
  float* rowsum = ctxnum + NSLOT * 2 * Bc * Cc;     // NSLOT*B*C   = 16384
  float* den    = rowsum + NSLOT * Bc * Cc;         // NSLOT*4     = 128
  float* sumsq  = den + NSLOT * 4;                  // NSLOT       = 32
  float* addv   = sumsq + NSLOT;                    // 2*B*C       = 1024

  hipMemsetAsync(d_ws, 0,
                 (NSLOT * (2 * Bc * Cc + Bc * Cc + 4 + 1)) * sizeof(float),
                 stream);

  gc_fused<<<dim3(GRIDX, Bc), TPB, 0, stream>>>(S, T, wms, bms, wmt, bmt,
                                                ctxnum, rowsum, den, sumsq);
  gc_k4a_mlp<<<4, 1024, 0, stream>>>(ctxnum, den, w1s, b1s, gs, bes, w2s, b2s,
                                     w1t, b1t, gt, bet, w2t, b2t, addv);
  gc_k4b_final<<<1, 256, 0, stream>>>(addv, rowsum, sumsq, out);
}

// Round 9
// 185.569 us; speedup vs baseline: 1.1992x; 1.0970x over previous
//
#include <hip/hip_runtime.h>
#include <math.h>

// Problem constants (match reference: B,C,W,H,D = 2,256,32,32,32)
#define Bc   2
#define Cc   256
#define Nn   32768            // W*H*D
#define CHc  128              // C/2
#define LN_EPS 1e-5f

// Fused-kernel tiling (R8's proven-best configuration)
#define TN    64              // spatial positions per tile (block)
#define TPB   512             // threads per block (8 waves)
#define NQ    16              // n-quads per tile (TN/4)
#define CG    32              // channel groups
#define CPG   8               // channels per group (Cc/CG)
#define GRIDX (Nn / TN)       // 512 -> x Bc = 1024 blocks
#define NSLOT 16              // atomic-contention slots

// Non-temporal float4 load: data is read EXACTLY once (zero reuse), so L2
// allocation (32MB agg vs 128MB stream) is pure thrash. nt skips it.
typedef float v4f __attribute__((ext_vector_type(4)));
static __device__ __forceinline__ float4 ntload4(const float* p) {
  v4f v = __builtin_nontemporal_load((const v4f*)p);
  return make_float4(v.x, v.y, v.z, v.w);
}

// ---------------------------------------------------------------------------
// R14 gc_fused: R8 VERBATIM (best measured: 45.5us) + non-temporal tile
// loads. Single-variable A/B vs R8.
//
// Evidence trail: R8=45.5 (6 barriers, cred LDS, NSLOT=16); R9 (1 barrier,
// butterfly)=52.9; R11 (2 barriers, 2 tiles)=47.5; R12 (TN=128)=47.2; R13
// (1 blk/CU pipeline)=51.5+spill. Occupancy/contiguity/barriers/atomics/
// prefetch ALL null -> invariant 2.8 TB/s effective (11 GB/s/CU vs m13's
// 25 GB/s/CU copy ceiling). Last untried axis: cache path. Streaming reads
// with zero reuse thrash L2; NT loads skip allocation.
// UNSHIFTED softmax (shift-invariant; |mask| <~ 2, fp32-exact).
// ---------------------------------------------------------------------------
__global__ __launch_bounds__(TPB, 2) void gc_fused(
    const float* __restrict__ S, const float* __restrict__ T,
    const float* __restrict__ wms, const float* __restrict__ bms,
    const float* __restrict__ wmt, const float* __restrict__ bmt,
    float* __restrict__ ctxnum,   // [NSLOT][2][Bc][Cc] raw weighted sums
    float* __restrict__ rowsum,   // [NSLOT][Bc][Cc]
    float* __restrict__ den,      // [NSLOT][4] softmax denominators (tt*2+b)
    float* __restrict__ sumsq) {  // [NSLOT]
  const int b    = blockIdx.y;
  const int tid  = threadIdx.x;
  const int nq   = tid & (NQ - 1);
  const int cg   = tid >> 4;
  const int wv   = tid >> 6;
  const int lane = tid & 63;
  const int c0   = cg * CPG;
  const int n0   = blockIdx.x * TN + nq * 4;
  const int slot = blockIdx.x & (NSLOT - 1);

  __shared__ float4 mredw[2][8][NQ];   // 4 KB   wave-level mask partials
  __shared__ float  cred[Cc * 17];     // 17 KB  reused channel-partial buffer
  __shared__ float  sqred[8];
  __shared__ float  denred[2][NQ];

  const float bS = bms[0];
  const float bT = bmt[0];

  const float* Sp = S + ((size_t)b * Cc + c0) * Nn + n0;
  const float* Tp = T + ((size_t)b * Cc + c0) * Nn + n0;

  // ---- issue all 16 independent tile loads up front (NON-TEMPORAL) ----
  float4 s4[CPG], t4[CPG];
#pragma unroll
  for (int i = 0; i < CPG; ++i) s4[i] = ntload4(Sp + (size_t)i * Nn);
#pragma unroll
  for (int i = 0; i < CPG; ++i) t4[i] = ntload4(Tp + (size_t)i * Nn);

  float wS[CPG], wT[CPG];
#pragma unroll
  for (int i = 0; i < CPG; ++i) { wS[i] = wms[c0 + i]; wT[i] = wmt[c0 + i]; }

  // ---- mask partials (only ms/mt accumulators live besides the tile) ----
  float4 ms = make_float4(0.f, 0.f, 0.f, 0.f);
  float4 mt = make_float4(0.f, 0.f, 0.f, 0.f);
#pragma unroll
  for (int i = 0; i < CPG; ++i) {
    ms.x += wS[i] * s4[i].x; ms.y += wS[i] * s4[i].y;
    ms.z += wS[i] * s4[i].z; ms.w += wS[i] * s4[i].w;
    mt.x += wT[i] * t4[i].x; mt.y += wT[i] * t4[i].y;
    mt.z += wT[i] * t4[i].z; mt.w += wT[i] * t4[i].w;
  }

  // butterfly across the wave's 4 cg-subgroups (lane bits 4,5) — no barrier
#pragma unroll
  for (int m = 16; m <= 32; m <<= 1) {
    ms.x += __shfl_xor(ms.x, m); ms.y += __shfl_xor(ms.y, m);
    ms.z += __shfl_xor(ms.z, m); ms.w += __shfl_xor(ms.w, m);
    mt.x += __shfl_xor(mt.x, m); mt.y += __shfl_xor(mt.y, m);
    mt.z += __shfl_xor(mt.z, m); mt.w += __shfl_xor(mt.w, m);
  }
  if (lane < NQ) { mredw[0][wv][nq] = ms; mredw[1][wv][nq] = mt; }

  __syncthreads();   // barrier 1: mask partials visible

  float4 Ms = make_float4(0.f, 0.f, 0.f, 0.f);
  float4 Mt = make_float4(0.f, 0.f, 0.f, 0.f);
#pragma unroll
  for (int w = 0; w < 8; ++w) {
    const float4 a = mredw[0][w][nq];
    Ms.x += a.x; Ms.y += a.y; Ms.z += a.z; Ms.w += a.w;
    const float4 c = mredw[1][w][nq];
    Mt.x += c.x; Mt.y += c.y; Mt.z += c.z; Mt.w += c.w;
  }
  float4 es, et;
  es.x = __expf(Ms.x + bS); es.y = __expf(Ms.y + bS);
  es.z = __expf(Ms.z + bS); es.w = __expf(Ms.w + bS);
  et.x = __expf(Mt.x + bT); et.y = __expf(Mt.y + bT);
  et.z = __expf(Mt.z + bT); et.w = __expf(Mt.w + bT);

  if (tid < NQ) {  // cg==0 threads: one denominator contribution per nq
    denred[0][tid] = es.x + es.y + es.z + es.w;
    denred[1][tid] = et.x + et.y + et.z + et.w;
  }

  // ---- round 1: ctx_s channel partials ----
#pragma unroll
  for (int i = 0; i < CPG; ++i)
    cred[(c0 + i) * 17 + nq] =
        s4[i].x * es.x + s4[i].y * es.y + s4[i].z * es.z + s4[i].w * es.w;
  __syncthreads();   // barrier 2
  if (tid < Cc) {
    float a = 0.f;
#pragma unroll
    for (int k = 0; k < NQ; ++k) a += cred[tid * 17 + k];
    atomicAdd(&ctxnum[(((size_t)slot * 2 + 0) * Bc + b) * Cc + tid], a);
  } else if (tid == Cc + 1) {
    float a = 0.f, c = 0.f;
#pragma unroll
    for (int k = 0; k < NQ; ++k) { a += denred[0][k]; c += denred[1][k]; }
    atomicAdd(&den[slot * 4 + 0 * Bc + b], a);
    atomicAdd(&den[slot * 4 + 1 * Bc + b], c);
  }
  __syncthreads();   // barrier 3 (cred write-after-read guard)

  // ---- round 2: ctx_t channel partials ----
#pragma unroll
  for (int i = 0; i < CPG; ++i)
    cred[(c0 + i) * 17 + nq] =
        t4[i].x * et.x + t4[i].y * et.y + t4[i].z * et.z + t4[i].w * et.w;
  __syncthreads();   // barrier 4
  if (tid < Cc) {
    float c = 0.f;
#pragma unroll
    for (int k = 0; k < NQ; ++k) c += cred[tid * 17 + k];
    atomicAdd(&ctxnum[(((size_t)slot * 2 + 1) * Bc + b) * Cc + tid], c);
  }
  __syncthreads();   // barrier 5

  // ---- round 3: rowsum partials + sumsq (recomputed from live s4/t4) ----
  float sq = 0.f;
#pragma unroll
  for (int i = 0; i < CPG; ++i) {
    const float dx = s4[i].x - t4[i].x, dy = s4[i].y - t4[i].y;
    const float dz = s4[i].z - t4[i].z, dw = s4[i].w - t4[i].w;
    cred[(c0 + i) * 17 + nq] = dx + dy + dz + dw;
    sq += dx * dx + dy * dy + dz * dz + dw * dw;
  }
#pragma unroll
  for (int m = 1; m < 64; m <<= 1) sq += __shfl_xor(sq, m);
  if (lane == 0) sqred[wv] = sq;
  __syncthreads();   // barrier 6
  if (tid < Cc) {
    float r = 0.f;
#pragma unroll
    for (int k = 0; k < NQ; ++k) r += cred[tid * 17 + k];
    atomicAdd(&rowsum[((size_t)slot * Bc + b) * Cc + tid], r);
  } else if (tid == Cc) {
    float v = 0.f;
#pragma unroll
    for (int w = 0; w < 8; ++w) v += sqred[w];
    atomicAdd(&sumsq[slot], v);
  }
}

// ---------------------------------------------------------------------------
// K4a: channel_add MLP per (tt,b). grid 4, block 1024. ctx = fold NSLOT
// slots at load time. w2 row preloaded early (fetch hides under stages 1-2).
// ---------------------------------------------------------------------------
__global__ __launch_bounds__(1024) void gc_k4a_mlp(
    const float* __restrict__ ctxr, const float* __restrict__ den,
    const float* __restrict__ w1s, const float* __restrict__ b1s,
    const float* __restrict__ gs,  const float* __restrict__ bes,
    const float* __restrict__ w2s, const float* __restrict__ b2s,
    const float* __restrict__ w1t, const float* __restrict__ b1t,
    const float* __restrict__ gt,  const float* __restrict__ bet,
    const float* __restrict__ w2t, const float* __restrict__ b2t,
    float* __restrict__ addv) {
  const int tt  = blockIdx.x >> 1;
  const int b   = blockIdx.x & 1;
  const int tid = threadIdx.x;

  const float* w1 = tt ? w1t : w1s;
  const float* b1 = tt ? b1t : b1s;
  const float* g  = tt ? gt  : gs;
  const float* be = tt ? bet : bes;
  const float* w2 = tt ? w2t : w2s;
  const float* b2 = tt ? b2t : b2s;

  __shared__ float cxs[Cc];
  __shared__ float part[1024];
  __shared__ float hbuf[CHc];
  __shared__ float hr[CHc];
  __shared__ float2 red2[128];
  __shared__ float mu_s, rstd_s;

  // ---- preload stage-3 weights early (consumed after LN) ----
  const int c3 = tid >> 2, q3 = tid & 3;
  const float* wr3 = w2 + c3 * CHc + q3 * 32;
  float4 w2r[8];
#pragma unroll
  for (int kk = 0; kk < 8; ++kk) w2r[kk] = *(const float4*)(wr3 + kk * 4);

  if (tid < Cc) {
    float num = 0.f, dn = 0.f;
#pragma unroll
    for (int kk = 0; kk < NSLOT; ++kk) {
      num += ctxr[(((size_t)kk * 2 + tt) * Bc + b) * Cc + tid];
      dn  += den[kk * 4 + tt * Bc + b];
    }
    cxs[tid] = num / dn;
  }
  __syncthreads();

  // stage 1: h[j] = sum_c ctx[c]*w1[j][c] + b1[j]   (128 j x 8 segments)
  {
    const int j = tid >> 3, s = tid & 7;
    const float* wr = w1 + j * Cc + s * 32;
    const float4* cx4 = (const float4*)(cxs + s * 32);
    float acc = 0.f;
#pragma unroll
    for (int kk = 0; kk < 8; ++kk) {
      const float4 w = *(const float4*)(wr + kk * 4);
      const float4 x = cx4[kk];
      acc += w.x * x.x + w.y * x.y + w.z * x.z + w.w * x.w;
    }
    part[tid] = acc;
  }
  __syncthreads();
  if (tid < CHc) {
    float h = b1[tid];
#pragma unroll
    for (int q = 0; q < 8; ++q) h += part[tid * 8 + q];
    hbuf[tid] = h;
  }
  __syncthreads();

  // LN stats over 128
  if (tid < CHc) {
    const float v = hbuf[tid];
    red2[tid] = make_float2(v, v * v);
  }
  __syncthreads();
  for (int s = 64; s > 0; s >>= 1) {
    if (tid < s) {
      red2[tid].x += red2[tid + s].x;
      red2[tid].y += red2[tid + s].y;
    }
    __syncthreads();
  }
  if (tid == 0) {
    const float mu = red2[0].x / (float)CHc;
    const float var = red2[0].y / (float)CHc - mu * mu;
    mu_s = mu;
    rstd_s = rsqrtf(var + LN_EPS);
  }
  __syncthreads();
  if (tid < CHc) {
    const float v = (hbuf[tid] - mu_s) * rstd_s * g[tid] + be[tid];
    hr[tid] = v > 0.f ? v : 0.f;
  }
  __syncthreads();

  // stage 3: addv[c] = sum_j hr[j]*w2[c][j] + b2[c]   (256 c x 4 segments)
  {
    const float4* h4 = (const float4*)(hr + q3 * 32);
    float acc = 0.f;
#pragma unroll
    for (int kk = 0; kk < 8; ++kk) {
      const float4 w = w2r[kk];
      const float4 x = h4[kk];
      acc += w.x * x.x + w.y * x.y + w.z * x.z + w.w * x.w;
    }
    part[tid] = acc;
  }
  __syncthreads();
  if (tid < Cc) {
    float acc = b2[tid];
#pragma unroll
    for (int q = 0; q < 4; ++q) acc += part[tid * 4 + q];
    addv[((size_t)tt * Bc + b) * Cc + tid] = acc;
  }
}

// ---------------------------------------------------------------------------
// K4b: final scalar. 1 block, 256 thr. Folds the NSLOT rowsum/sumsq slots.
// out = (sumsq + sum_{b,c} [2*delta*rowsum + N*delta^2]) / B
// ---------------------------------------------------------------------------
__global__ __launch_bounds__(256) void gc_k4b_final(
    const float* __restrict__ addv, const float* __restrict__ rowsum,
    const float* __restrict__ sumsq, float* __restrict__ out) {
  const int tid = threadIdx.x;
  __shared__ float red[256];
  float part = 0.f;
  for (int job = tid; job < Bc * Cc; job += 256) {
    const int c = job & (Cc - 1);
    const int b = job >> 8;
    const float delta = addv[((size_t)0 * Bc + b) * Cc + c] -
                        addv[((size_t)1 * Bc + b) * Cc + c];
    float rs = 0.f;
#pragma unroll
    for (int k = 0; k < NSLOT; ++k)
      rs += rowsum[((size_t)k * Bc + b) * Cc + c];
    part += 2.f * delta * rs + (float)Nn * delta * delta;
  }
  red[tid] = part;
  __syncthreads();
  for (int s = 128; s > 0; s >>= 1) {
    if (tid < s) red[tid] += red[tid + s];
    __syncthreads();
  }
  if (tid == 0) {
    float sq = 0.f;
#pragma unroll
    for (int k = 0; k < NSLOT; ++k) sq += sumsq[k];
    out[0] = (red[0] + sq) / (float)Bc;
  }
}

// ---------------------------------------------------------------------------
extern "C" void kernel_launch(void* const* d_in, const int* in_sizes, int n_in,
                              void* d_out, int out_size, void* d_ws,
                              size_t ws_size, hipStream_t stream) {
  const float* S   = (const float*)d_in[0];
  const float* T   = (const float*)d_in[1];
  const float* wms = (const float*)d_in[2];
  const float* bms = (const float*)d_in[3];
  const float* wmt = (const float*)d_in[4];
  const float* bmt = (const float*)d_in[5];
  const float* w1s = (const float*)d_in[6];
  const float* b1s = (const float*)d_in[7];
  const float* gs  = (const float*)d_in[8];
  const float* bes = (const float*)d_in[9];
  const float* w2s = (const float*)d_in[10];
  const float* b2s = (const float*)d_in[11];
  const float* w1t = (const float*)d_in[12];
  const float* b1t = (const float*)d_in[13];
  const float* gt  = (const float*)d_in[14];
  const float* bet = (const float*)d_in[15];
  const float* w2t = (const float*)d_in[16];
  const float* b2t = (const float*)d_in[17];
  float* out = (float*)d_out;

  // ws layout (floats) — slotted accumulators first; one memset zeroes all.
  float* ws     = (float*)d_ws;
  float* ctxnum = ws;                               // NSLOT*2*B*C = 16384
  float* rowsum = ctxnum + NSLOT * 2 * Bc * Cc;     // NSLOT*B*C   = 8192
  float* den    = rowsum + NSLOT * Bc * Cc;         // NSLOT*4     = 64
  float* sumsq  = den + NSLOT * 4;                  // NSLOT       = 16
  float* addv   = sumsq + NSLOT;                    // 2*B*C       = 1024

  hipMemsetAsync(d_ws, 0,
                 (NSLOT * (2 * Bc * Cc + Bc * Cc + 4 + 1)) * sizeof(float),
                 stream);

  gc_fused<<<dim3(GRIDX, Bc), TPB, 0, stream>>>(S, T, wms, bms, wmt, bmt,
                                                ctxnum, rowsum, den, sumsq);
  gc_k4a_mlp<<<4, 1024, 0, stream>>>(ctxnum, den, w1s, b1s, gs, bes, w2s, b2s,
                                     w1t, b1t, gt, bet, w2t, b2t, addv);
  gc_k4b_final<<<1, 256, 0, stream>>>(addv, rowsum, sumsq, out);
}